// Round 5
// baseline (47.724 us; speedup 1.0000x reference)
//
#include <hip/hip_runtime.h>
#include <hip/hip_bf16.h>

// y = upsample_nearest_2x2x2(conv1x1(x,W,b)); conv on small grid via bf16 MFMA, replicate 8x.
// x: [2][320][16][32][32] f32, W: [160][320] f32, b: [160] f32 -> out: [2][160][32][64][64] f32
//
// Pre-kernel: W -> bf16, written to d_ws as 5 chunk-images (20480 B each) in LDS byte
// order with XOR bank-swizzle pre-baked:  image[a] = Wbf[o][k(a ^ ((o&7)<<4))].
// Main kernel: 1024 blocks (512 spatial tiles x 2 batch), 4 blocks/CU; W staged by
// global_load_lds (16B) straight from the ws image; X reg-staged f32->bf16 transpose.

#define CI      320
#define CO      160
#define S_IN    16384       // 16*32*32
#define KC      64          // K chunk = 2 MFMA K-steps
#define NT      32          // spatial tile per block
#define NCHUNK  (CI / KC)   // 5
#define MT      5           // M-tiles per wave (80 o per wave-half)
#define WCH_B   (CO * KC * 2)       // 20480 bytes per W chunk image
#define WS_B    (NCHUNK * WCH_B)    // 102400 bytes total

typedef __attribute__((ext_vector_type(8))) short short8;
typedef __attribute__((ext_vector_type(4))) float f32x4;

static __device__ __forceinline__ unsigned short f2bf(float f) {
    __hip_bfloat16 h = __float2bfloat16(f);   // RNE
    unsigned short u;
    __builtin_memcpy(&u, &h, 2);
    return u;
}
static __device__ __forceinline__ unsigned int pack2(float lo, float hi) {
    return (unsigned int)f2bf(lo) | ((unsigned int)f2bf(hi) << 16);
}

// ---- pre-kernel: build swizzled bf16 W image in d_ws (25600 u32) ----
__global__ __launch_bounds__(256) void wprep_kernel(
    const float* __restrict__ Wm, unsigned int* __restrict__ ws)
{
    const int i = blockIdx.x * 256 + threadIdx.x;   // 0..25599
    const int c = i / 5120;                          // chunk
    const int r = i - c * 5120;                      // u32 within chunk
    const int o = r >> 5;                            // 32 u32 per o-row
    const int inner   = (r & 31) << 2;               // byte within row, pre-swizzle
    const int innersw = inner ^ ((o & 7) << 4);      // involution
    const int k = c * 64 + (innersw >> 1);           // even
    ws[i] = pack2(Wm[o * CI + k], Wm[o * CI + k + 1]);
}

template<bool USE_WS>
__global__ __launch_bounds__(256, 4) void fused_upconv_mfma(
    const float* __restrict__ x,
    const float* __restrict__ Wm,
    const float* __restrict__ bias,
    const unsigned int* __restrict__ wsW,
    float* __restrict__ out)
{
    __shared__ __align__(16) unsigned int XsU[NT][36];   // [s][k/2] padded rows 144B, 4.5 KB
    __shared__ __align__(16) unsigned int WsU[WCH_B / 4]; // linear swizzled image, 20 KB

    const int t  = threadIdx.x;
    const int bx = blockIdx.x;              // 0..1023
    const int tile = bx >> 1;               // 0..511
    const int b    = bx & 1;
    const int s_base = tile * NT;
    const float* xb  = x + (size_t)b * CI * S_IN;

    const int lane = t & 63;
    const int wid  = t >> 6;
    const int sh   = wid & 1;               // s-half (16 s)
    const int ohh  = wid >> 1;              // o-half (80 o)
    const int frow = lane & 15;
    const int fk   = lane >> 4;
    const int o_base = ohh * 80;

    // X staging map: kp = t>>3 (32 k-pairs), s4 = (t&7)*4
    const int kp = t >> 3;
    const int s4 = (t & 7) * 4;
    float4 xr0, xr1;
    float4 wr[10];                          // only used when !USE_WS

    char* WsB = (char*)WsU;

    // ---- prologue: prefetch chunk 0 ----
    xr0 = *(const float4*)&xb[(size_t)(2 * kp)     * S_IN + s_base + s4];
    xr1 = *(const float4*)&xb[(size_t)(2 * kp + 1) * S_IN + s_base + s4];
    if constexpr (USE_WS) {
        const char* g = (const char*)wsW + (size_t)(wid * 5) * 1024 + lane * 16;
        char* l = WsB + (wid * 5) * 1024;   // wave-uniform; HW adds lane*16
        #pragma unroll
        for (int i = 0; i < 5; ++i)
            __builtin_amdgcn_global_load_lds(
                (const __attribute__((address_space(1))) unsigned int*)(g + i * 1024),
                (__attribute__((address_space(3))) unsigned int*)(l + i * 1024),
                16, 0, 0);
    } else {
        #pragma unroll
        for (int it = 0; it < 10; ++it) {
            const int idx = t + it * 256;
            wr[it] = *(const float4*)&Wm[(size_t)(idx >> 4) * CI + (idx & 15) * 4];
        }
    }

    f32x4 acc[MT];
    #pragma unroll
    for (int mt = 0; mt < MT; ++mt) acc[mt] = (f32x4){0.f, 0.f, 0.f, 0.f};

    const char* xrow = (const char*)(&XsU[sh * 16 + frow][0]) + fk * 16;

    for (int c = 0; c < NCHUNK; ++c) {
        __syncthreads();    // prev compute done; (vmcnt/lgkm drained by compiler)

        if constexpr (USE_WS) {
            if (c > 0) {    // issue W(c) gload_lds into the now-free buffer
                const char* g = (const char*)wsW + (size_t)c * WCH_B
                              + (size_t)(wid * 5) * 1024 + lane * 16;
                char* l = WsB + (wid * 5) * 1024;
                #pragma unroll
                for (int i = 0; i < 5; ++i)
                    __builtin_amdgcn_global_load_lds(
                        (const __attribute__((address_space(1))) unsigned int*)(g + i * 1024),
                        (__attribute__((address_space(3))) unsigned int*)(l + i * 1024),
                        16, 0, 0);
            }
        } else {
            #pragma unroll
            for (int it = 0; it < 10; ++it) {
                const int idx = t + it * 256;
                const int o = idx >> 4, kq = idx & 15;
                uint2 p = make_uint2(pack2(wr[it].x, wr[it].y), pack2(wr[it].z, wr[it].w));
                *(uint2*)&WsB[o * 128 + ((kq * 8) ^ ((o & 7) << 4))] = p;
            }
        }

        // X regs -> LDS (f32->bf16; [k][s] -> [s][k] transpose)
        {
            const float a0[4] = {xr0.x, xr0.y, xr0.z, xr0.w};
            const float a1[4] = {xr1.x, xr1.y, xr1.z, xr1.w};
            #pragma unroll
            for (int j = 0; j < 4; ++j)
                XsU[s4 + j][kp] = pack2(a0[j], a1[j]);
        }
        __syncthreads();    // drains W gload_lds (vmcnt 0) + X writes

        // prefetch next chunk operands (overlaps MFMA)
        if (c < NCHUNK - 1) {
            const int kc = (c + 1) * KC;
            xr0 = *(const float4*)&xb[(size_t)(kc + 2 * kp)     * S_IN + s_base + s4];
            xr1 = *(const float4*)&xb[(size_t)(kc + 2 * kp + 1) * S_IN + s_base + s4];
            if constexpr (!USE_WS) {
                #pragma unroll
                for (int it = 0; it < 10; ++it) {
                    const int idx = t + it * 256;
                    wr[it] = *(const float4*)&Wm[(size_t)(idx >> 4) * CI + kc + (idx & 15) * 4];
                }
            }
        }

        // 2 K-steps x 5 M-tiles
        #pragma unroll
        for (int st = 0; st < 2; ++st) {
            const short8 bfrag = *(const short8*)(xrow + st * 64);
            #pragma unroll
            for (int mt = 0; mt < MT; ++mt) {
                const int o = o_base + mt * 16 + frow;
                const short8 afrag = *(const short8*)
                    (WsB + o * 128 + ((st * 64 + fk * 16) ^ ((frow & 7) << 4)));
                acc[mt] = __builtin_amdgcn_mfma_f32_16x16x32_bf16(afrag, bfrag, acc[mt], 0, 0, 0);
            }
        }
    }

    // ---- epilogue: bias + replicate 8x; shfl-pair -> full float4 nontemporal stores ----
    const int s   = s_base + sh * 16 + frow;    // D col = s
    const int dd  = s >> 10;
    const int hh  = (s >> 5) & 31;
    const int wc  = s & 31;
    const int odd = lane & 1;
    const int wc0 = wc & ~1;

    #pragma unroll
    for (int mt = 0; mt < MT; ++mt) {
        #pragma unroll
        for (int j = 0; j < 4; ++j) {
            const int o = o_base + mt * 16 + fk * 4 + j;   // D row = o
            float v  = acc[mt][j] + bias[o];
            float vp = __shfl_xor(v, 1);
            float lo = odd ? vp : v;
            float hi = odd ? v : vp;
            f32x4 q = {lo, lo, hi, hi};
            const size_t base = (((size_t)(b * CO + o) * 32) + (size_t)(2 * dd + odd)) * 4096
                              + (size_t)(2 * hh) * 64 + (size_t)(2 * wc0);
            __builtin_nontemporal_store(q, (f32x4*)&out[base]);
            __builtin_nontemporal_store(q, (f32x4*)&out[base + 64]);
        }
    }
}

extern "C" void kernel_launch(void* const* d_in, const int* in_sizes, int n_in,
                              void* d_out, int out_size, void* d_ws, size_t ws_size,
                              hipStream_t stream) {
    const float* x    = (const float*)d_in[0];
    const float* Wm   = (const float*)d_in[1];
    const float* bias = (const float*)d_in[2];
    float* out        = (float*)d_out;

    dim3 block(256);
    if (ws_size >= (size_t)WS_B && d_ws != nullptr) {
        unsigned int* ws = (unsigned int*)d_ws;
        wprep_kernel<<<dim3(100), block, 0, stream>>>(Wm, ws);
        fused_upconv_mfma<true><<<dim3(1024), block, 0, stream>>>(x, Wm, bias, ws, out);
    } else {
        fused_upconv_mfma<false><<<dim3(1024), block, 0, stream>>>(x, Wm, bias, nullptr, out);
    }
}